// Round 1
// baseline (1262.325 us; speedup 1.0000x reference)
//
#include <hip/hip_runtime.h>
#include <hip/hip_bf16.h>

// Problem constants
constexpr int S      = 4096;
constexpr int DMODEL = 1024;
constexpr int H      = 16;
constexpr int DK     = 64;

// ---------------------------------------------------------------------------
// fp32 tiled GEMM body: C[M x 1024] = X[M x 1024] @ B[1024 x 1024]
// HEADED: B[d][n] = W[n>>6][d][n&63]  (per-head projection weights [H][D][DK])
// else:   B[d][n] = W[d*1024 + n]     (flat W_O)
// Tile: 128(M) x 64(N), KB=32. 256 threads, each computes 8x4 outputs.
// ---------------------------------------------------------------------------
template <bool HEADED>
__device__ __forceinline__ void gemm_body(const float* __restrict__ X,
                                          const float* __restrict__ W,
                                          float* __restrict__ C,
                                          int m0, int n0)
{
    __shared__ float As[128][33];
    __shared__ float Bs[32][64];

    const int t  = threadIdx.x;
    const int tx = t & 15;   // N direction (4 cols each)
    const int ty = t >> 4;   // M direction (8 rows each)

    float acc[8][4] = {};

    for (int k0 = 0; k0 < 1024; k0 += 32) {
        // Load A tile 128x32 (coalesced: 2 rows x 32 cols per wave-read)
        {
            const int c  = t & 31;
            const int r0 = t >> 5;
#pragma unroll
            for (int rr = 0; rr < 16; ++rr) {
                const int r = r0 + rr * 8;
                As[r][c] = X[(m0 + r) * 1024 + k0 + c];
            }
        }
        // Load B tile 32x64 (coalesced along n)
        {
            const int j  = t & 63;
            const int c0 = t >> 6;
#pragma unroll
            for (int cc = 0; cc < 8; ++cc) {
                const int c = c0 + cc * 4;
                const int d = k0 + c;
                const int n = n0 + j;
                float v;
                if (HEADED)
                    v = W[(n >> 6) * (1024 * 64) + d * 64 + (n & 63)];
                else
                    v = W[d * 1024 + n];
                Bs[c][j] = v;
            }
        }
        __syncthreads();

#pragma unroll
        for (int kk = 0; kk < 32; ++kk) {
            float a[8];
#pragma unroll
            for (int i = 0; i < 8; ++i) a[i] = As[ty * 8 + i][kk];
            const float4 bv = *reinterpret_cast<const float4*>(&Bs[kk][tx * 4]);
            const float b[4] = {bv.x, bv.y, bv.z, bv.w};
#pragma unroll
            for (int i = 0; i < 8; ++i)
#pragma unroll
                for (int j = 0; j < 4; ++j) acc[i][j] += a[i] * b[j];
        }
        __syncthreads();
    }

#pragma unroll
    for (int i = 0; i < 8; ++i) {
        const int m = m0 + ty * 8 + i;
        float4 o = make_float4(acc[i][0], acc[i][1], acc[i][2], acc[i][3]);
        *reinterpret_cast<float4*>(&C[m * 1024 + n0 + tx * 4]) = o;
    }
}

// Projections: z = 0/1/2 -> Qc/Kc/Vc in concat layout [S][h*64+k]
__global__ __launch_bounds__(256) void proj_all(const float* __restrict__ Q,
                                                const float* __restrict__ K,
                                                const float* __restrict__ V,
                                                const float* __restrict__ WQ,
                                                const float* __restrict__ WK,
                                                const float* __restrict__ WV,
                                                float* __restrict__ Qc,
                                                float* __restrict__ Kc,
                                                float* __restrict__ Vc)
{
    const float* X;
    const float* W;
    float* C;
    if (blockIdx.z == 0)      { X = Q; W = WQ; C = Qc; }
    else if (blockIdx.z == 1) { X = K; W = WK; C = Kc; }
    else                      { X = V; W = WV; C = Vc; }
    gemm_body<true>(X, W, C, blockIdx.x * 128, blockIdx.y * 64);
}

__global__ __launch_bounds__(256) void out_gemm(const float* __restrict__ A,
                                                const float* __restrict__ W,
                                                float* __restrict__ C)
{
    gemm_body<false>(A, W, C, blockIdx.x * 128, blockIdx.y * 64);
}

// ---------------------------------------------------------------------------
// Flash-style causal attention, fp32. One block = (head h, 64-row Q tile).
// Online softmax; scores = (Qh . Kh)/8, masked j>q -> -1e9 (matches ref).
// ---------------------------------------------------------------------------
__global__ __launch_bounds__(256) void attn(const float* __restrict__ Qc,
                                            const float* __restrict__ Kc,
                                            const float* __restrict__ Vc,
                                            float* __restrict__ Oc)
{
    const int bid = blockIdx.x;
    const int h   = bid & 15;
    const int qt  = 63 - (bid >> 4);   // longest-running tiles dispatch first
    const int q0  = qt * 64;

    __shared__ float Qs[64][68];
    __shared__ float KP[64][68];   // K tile, reused to hold P
    __shared__ float Vs[64][68];
    __shared__ float m_s[64], l_s[64], al_s[64];
    __shared__ float red[64][17];

    const int t  = threadIdx.x;
    const int tx = t & 15;   // 4 cols (j or d) each
    const int ty = t >> 4;   // 4 rows (q) each

    // Load Q tile
#pragma unroll
    for (int i = 0; i < 16; ++i) {
        const int idx = t + i * 256;
        const int r = idx >> 6, c = idx & 63;
        Qs[r][c] = Qc[(q0 + r) * 1024 + h * 64 + c];
    }
    if (t < 64) { m_s[t] = -3e38f; l_s[t] = 0.f; }
    float acc[4][4] = {};
    __syncthreads();

    for (int jt = 0; jt <= qt; ++jt) {
        const int j0 = jt * 64;
        // Load K and V tiles
#pragma unroll
        for (int i = 0; i < 16; ++i) {
            const int idx = t + i * 256;
            const int r = idx >> 6, c = idx & 63;
            KP[r][c] = Kc[(j0 + r) * 1024 + h * 64 + c];
            Vs[r][c] = Vc[(j0 + r) * 1024 + h * 64 + c];
        }
        __syncthreads();   // (A)

        // Scores s[4][4]: rows q = ty*4+i, cols j = tx*4+jj
        float s[4][4] = {};
#pragma unroll
        for (int k4 = 0; k4 < 64; k4 += 4) {
            float4 a4[4], b4[4];
#pragma unroll
            for (int i = 0; i < 4; ++i)
                a4[i] = *reinterpret_cast<const float4*>(&Qs[ty * 4 + i][k4]);
#pragma unroll
            for (int j = 0; j < 4; ++j)
                b4[j] = *reinterpret_cast<const float4*>(&KP[tx * 4 + j][k4]);
#pragma unroll
            for (int i = 0; i < 4; ++i)
#pragma unroll
                for (int j = 0; j < 4; ++j)
                    s[i][j] += a4[i].x * b4[j].x + a4[i].y * b4[j].y +
                               a4[i].z * b4[j].z + a4[i].w * b4[j].w;
        }
        // Scale + causal mask (jg > q -> -1e9; only bites on diagonal tile)
#pragma unroll
        for (int i = 0; i < 4; ++i) {
            const int q = q0 + ty * 4 + i;
#pragma unroll
            for (int j = 0; j < 4; ++j) {
                float v = s[i][j] * 0.125f;
                const int jg = j0 + tx * 4 + j;
                s[i][j] = (jg > q) ? -1e9f : v;
            }
        }

        // Row max: partial per-thread, reduce across the 16 tx threads
#pragma unroll
        for (int i = 0; i < 4; ++i) {
            const float lm = fmaxf(fmaxf(s[i][0], s[i][1]), fmaxf(s[i][2], s[i][3]));
            red[ty * 4 + i][tx] = lm;
        }
        __syncthreads();   // (B) — also: all K reads from KP complete
        if (t < 64) {
            const float m_old = m_s[t];
            float mt = red[t][0];
#pragma unroll
            for (int x = 1; x < 16; ++x) mt = fmaxf(mt, red[t][x]);
            const float m_new = fmaxf(m_old, mt);
            m_s[t]  = m_new;
            al_s[t] = __expf(m_old - m_new);
        }
        __syncthreads();   // (C)

        // p = exp(s - m), partial row sums, rescale acc, write P into KP
#pragma unroll
        for (int i = 0; i < 4; ++i) {
            const int q = ty * 4 + i;
            const float mn = m_s[q];
            const float al = al_s[q];
            float p[4];
            float sum = 0.f;
#pragma unroll
            for (int j = 0; j < 4; ++j) { p[j] = __expf(s[i][j] - mn); sum += p[j]; }
            red[q][tx] = sum;
            *reinterpret_cast<float4*>(&KP[q][tx * 4]) = make_float4(p[0], p[1], p[2], p[3]);
#pragma unroll
            for (int d = 0; d < 4; ++d) acc[i][d] *= al;
        }
        __syncthreads();   // (D)
        if (t < 64) {
            float sum = 0.f;
#pragma unroll
            for (int x = 0; x < 16; ++x) sum += red[t][x];
            l_s[t] = l_s[t] * al_s[t] + sum;
        }

        // O += P @ V
#pragma unroll
        for (int kk = 0; kk < 64; ++kk) {
            const float4 v4 = *reinterpret_cast<const float4*>(&Vs[kk][tx * 4]);
            float pr[4];
#pragma unroll
            for (int i = 0; i < 4; ++i) pr[i] = KP[ty * 4 + i][kk];
#pragma unroll
            for (int i = 0; i < 4; ++i) {
                acc[i][0] += pr[i] * v4.x;
                acc[i][1] += pr[i] * v4.y;
                acc[i][2] += pr[i] * v4.z;
                acc[i][3] += pr[i] * v4.w;
            }
        }
        __syncthreads();   // (E) — protect KP/Vs before next load, l_s/red reuse
    }

    // Epilogue: normalize and write head output into concat layout
#pragma unroll
    for (int i = 0; i < 4; ++i) {
        const int q = ty * 4 + i;
        const float inv = 1.f / l_s[q];
        const int m = q0 + q;
        float4 o = make_float4(acc[i][0] * inv, acc[i][1] * inv,
                               acc[i][2] * inv, acc[i][3] * inv);
        *reinterpret_cast<float4*>(&Oc[m * 1024 + h * 64 + tx * 4]) = o;
    }
}

extern "C" void kernel_launch(void* const* d_in, const int* in_sizes, int n_in,
                              void* d_out, int out_size, void* d_ws, size_t ws_size,
                              hipStream_t stream)
{
    const float* Q  = (const float*)d_in[0];
    const float* K  = (const float*)d_in[1];
    const float* V  = (const float*)d_in[2];
    const float* WQ = (const float*)d_in[3];
    const float* WK = (const float*)d_in[4];
    const float* WV = (const float*)d_in[5];
    const float* WO = (const float*)d_in[6];
    // d_in[7] = mask scalar (always 1; causal mask applied unconditionally)

    float* out = (float*)d_out;
    float* ws  = (float*)d_ws;

    const size_t SD = (size_t)S * DMODEL;
    float* Qc = ws;
    float* Kc = ws + SD;
    float* Vc = ws + 2 * SD;
    float* Oc = ws + 3 * SD;

    // 1) Per-head projections into concat layout [S][h*64+k]
    proj_all<<<dim3(S / 128, DMODEL / 64, 3), 256, 0, stream>>>(
        Q, K, V, WQ, WK, WV, Qc, Kc, Vc);

    // 2) Causal flash attention per (head, 64-row Q tile)
    attn<<<dim3((S / 64) * H), 256, 0, stream>>>(Qc, Kc, Vc, Oc);

    // 3) Output projection: out = Oc @ W_O
    out_gemm<<<dim3(S / 128, DMODEL / 64), 256, 0, stream>>>(Oc, WO, out);
}

// Round 2
// 744.456 us; speedup vs baseline: 1.6956x; 1.6956x over previous
//
#include <hip/hip_runtime.h>
#include <hip/hip_bf16.h>

// Problem constants
constexpr int S      = 4096;
constexpr int DMODEL = 1024;
constexpr int H      = 16;
constexpr int DK     = 64;

typedef __attribute__((ext_vector_type(8))) short  short8;
typedef __attribute__((ext_vector_type(4))) short  short4v;
typedef __attribute__((ext_vector_type(4))) float  float4v;

// RNE float -> bf16 (bit pattern), and back
__device__ __forceinline__ unsigned short f2bf(float x) {
    unsigned u = __builtin_bit_cast(unsigned, x);
    u += 0x7FFFu + ((u >> 16) & 1u);
    return (unsigned short)(u >> 16);
}
__device__ __forceinline__ float bf2f(unsigned short h) {
    unsigned u = ((unsigned)h) << 16;
    return __builtin_bit_cast(float, u);
}

// ---------------------------------------------------------------------------
// fp32 tiled GEMM body (unchanged, known-good): C[Mx1024] = X[Mx1024] @ B
// ---------------------------------------------------------------------------
template <bool HEADED>
__device__ __forceinline__ void gemm_body(const float* __restrict__ X,
                                          const float* __restrict__ W,
                                          float* __restrict__ C,
                                          int m0, int n0)
{
    __shared__ float As[128][33];
    __shared__ float Bs[32][64];

    const int t  = threadIdx.x;
    const int tx = t & 15;
    const int ty = t >> 4;

    float acc[8][4] = {};

    for (int k0 = 0; k0 < 1024; k0 += 32) {
        {
            const int c  = t & 31;
            const int r0 = t >> 5;
#pragma unroll
            for (int rr = 0; rr < 16; ++rr) {
                const int r = r0 + rr * 8;
                As[r][c] = X[(m0 + r) * 1024 + k0 + c];
            }
        }
        {
            const int j  = t & 63;
            const int c0 = t >> 6;
#pragma unroll
            for (int cc = 0; cc < 8; ++cc) {
                const int c = c0 + cc * 4;
                const int d = k0 + c;
                const int n = n0 + j;
                float v;
                if (HEADED)
                    v = W[(n >> 6) * (1024 * 64) + d * 64 + (n & 63)];
                else
                    v = W[d * 1024 + n];
                Bs[c][j] = v;
            }
        }
        __syncthreads();

#pragma unroll
        for (int kk = 0; kk < 32; ++kk) {
            float a[8];
#pragma unroll
            for (int i = 0; i < 8; ++i) a[i] = As[ty * 8 + i][kk];
            const float4 bv = *reinterpret_cast<const float4*>(&Bs[kk][tx * 4]);
            const float b[4] = {bv.x, bv.y, bv.z, bv.w};
#pragma unroll
            for (int i = 0; i < 8; ++i)
#pragma unroll
                for (int j = 0; j < 4; ++j) acc[i][j] += a[i] * b[j];
        }
        __syncthreads();
    }

#pragma unroll
    for (int i = 0; i < 8; ++i) {
        const int m = m0 + ty * 8 + i;
        float4 o = make_float4(acc[i][0], acc[i][1], acc[i][2], acc[i][3]);
        *reinterpret_cast<float4*>(&C[m * 1024 + n0 + tx * 4]) = o;
    }
}

__global__ __launch_bounds__(256) void proj_all(const float* __restrict__ Q,
                                                const float* __restrict__ K,
                                                const float* __restrict__ V,
                                                const float* __restrict__ WQ,
                                                const float* __restrict__ WK,
                                                const float* __restrict__ WV,
                                                float* __restrict__ Qc,
                                                float* __restrict__ Kc,
                                                float* __restrict__ Vc)
{
    const float* X;
    const float* W;
    float* C;
    if (blockIdx.z == 0)      { X = Q; W = WQ; C = Qc; }
    else if (blockIdx.z == 1) { X = K; W = WK; C = Kc; }
    else                      { X = V; W = WV; C = Vc; }
    gemm_body<true>(X, W, C, blockIdx.x * 128, blockIdx.y * 64);
}

__global__ __launch_bounds__(256) void out_gemm(const float* __restrict__ A,
                                                const float* __restrict__ W,
                                                float* __restrict__ C)
{
    gemm_body<false>(A, W, C, blockIdx.x * 128, blockIdx.y * 64);
}

// ---------------------------------------------------------------------------
// MFMA flash attention. One block = (head, 64-row Q tile), 4 waves.
// Wave w owns q-rows [w*16, w*16+16).
// 16x16x32 bf16 MFMA layouts:
//   A-frag: lane holds A[m=lane&15][k=quad*8+j], j=0..7   (quad = lane>>4)
//   B-frag: lane holds B[k=quad*8+j][n=lane&15]
//   C/D:    lane holds C[row=quad*4+reg][col=lane&15]
// Score path split-bf16 (hi+lo): S = Qhi*Khi + Qhi*Klo + Qlo*Khi  (~fp32 acc)
// PV path plain bf16. V staged transposed in LDS so B-frags are ds_read_b128.
// ---------------------------------------------------------------------------
__global__ __launch_bounds__(256) void attn_mfma(const float* __restrict__ Qc,
                                                 const float* __restrict__ Kc,
                                                 const float* __restrict__ Vc,
                                                 float* __restrict__ Oc)
{
    __shared__ __align__(16) short Khi[64][72];   // [key][dk] bf16 hi
    __shared__ __align__(16) short Klo[64][72];   // [key][dk] bf16 lo
    __shared__ __align__(16) short Vts[64][72];   // [dk][key] bf16 (transposed)
    __shared__ __align__(16) short Pb[4][16][72]; // per-wave P strip [q][key]

    const int bid = blockIdx.x;
    const int h   = bid & 15;
    const int qt  = 63 - (bid >> 4);   // longest tiles dispatch first
    const int q0  = qt * 64;

    const int t    = threadIdx.x;
    const int wave = t >> 6;
    const int lane = t & 63;
    const int quad = lane >> 4;
    const int l15  = lane & 15;

    // --- Q A-fragments, split hi/lo, loaded once straight from global ---
    short8 qhi[2], qlo[2];
    {
        const int qrow = q0 + wave * 16 + l15;
        const float* qp = Qc + (size_t)qrow * DMODEL + h * 64 + quad * 8;
#pragma unroll
        for (int ks = 0; ks < 2; ++ks) {
            float4 a = *(const float4*)(qp + ks * 32);
            float4 b = *(const float4*)(qp + ks * 32 + 4);
            const float xs[8] = {a.x, a.y, a.z, a.w, b.x, b.y, b.z, b.w};
#pragma unroll
            for (int j = 0; j < 8; ++j) {
                const unsigned short hi = f2bf(xs[j]);
                const unsigned short lo = f2bf(xs[j] - bf2f(hi));
                qhi[ks][j] = (short)hi;
                qlo[ks][j] = (short)lo;
            }
        }
    }

    float m_r[4] = {-1e30f, -1e30f, -1e30f, -1e30f};
    float l_r[4] = {0.f, 0.f, 0.f, 0.f};
    float4v oacc[4];
#pragma unroll
    for (int nt = 0; nt < 4; ++nt)
#pragma unroll
        for (int r = 0; r < 4; ++r) oacc[nt][r] = 0.f;

    const int sr  = t >> 2;          // staging row (key index 0..63)
    const int sc0 = (t & 3) * 16;    // staging col base (dk)

    for (int jt = 0; jt <= qt; ++jt) {
        const int j0 = jt * 64;
        const float* kp = Kc + (size_t)(j0 + sr) * DMODEL + h * 64 + sc0;
        const float* vp = Vc + (size_t)(j0 + sr) * DMODEL + h * 64 + sc0;
#pragma unroll
        for (int ch = 0; ch < 4; ++ch) {
            const float4 f = *(const float4*)(kp + ch * 4);
            const float xs[4] = {f.x, f.y, f.z, f.w};
            short4v hv, lv;
#pragma unroll
            for (int j = 0; j < 4; ++j) {
                const unsigned short hi = f2bf(xs[j]);
                const unsigned short lo = f2bf(xs[j] - bf2f(hi));
                hv[j] = (short)hi;
                lv[j] = (short)lo;
            }
            *(short4v*)&Khi[sr][sc0 + ch * 4] = hv;
            *(short4v*)&Klo[sr][sc0 + ch * 4] = lv;
            const float4 g = *(const float4*)(vp + ch * 4);
            Vts[sc0 + ch * 4 + 0][sr] = (short)f2bf(g.x);
            Vts[sc0 + ch * 4 + 1][sr] = (short)f2bf(g.y);
            Vts[sc0 + ch * 4 + 2][sr] = (short)f2bf(g.z);
            Vts[sc0 + ch * 4 + 3][sr] = (short)f2bf(g.w);
        }
        __syncthreads();   // staging complete

        // --- S = Q K^T (split bf16, fp32 accum) ---
        float4v sacc[4];
#pragma unroll
        for (int nt = 0; nt < 4; ++nt)
#pragma unroll
            for (int r = 0; r < 4; ++r) sacc[nt][r] = 0.f;
#pragma unroll
        for (int nt = 0; nt < 4; ++nt) {
            const int key = nt * 16 + l15;
#pragma unroll
            for (int ks = 0; ks < 2; ++ks) {
                const short8 bh = *(const short8*)&Khi[key][ks * 32 + quad * 8];
                const short8 bl = *(const short8*)&Klo[key][ks * 32 + quad * 8];
                sacc[nt] = __builtin_amdgcn_mfma_f32_16x16x32_bf16(qhi[ks], bh, sacc[nt], 0, 0, 0);
                sacc[nt] = __builtin_amdgcn_mfma_f32_16x16x32_bf16(qhi[ks], bl, sacc[nt], 0, 0, 0);
                sacc[nt] = __builtin_amdgcn_mfma_f32_16x16x32_bf16(qlo[ks], bh, sacc[nt], 0, 0, 0);
            }
        }

        // --- scale + causal mask (exactly -1e9 at masked, matches ref) ---
#pragma unroll
        for (int nt = 0; nt < 4; ++nt) {
            const int jg = j0 + nt * 16 + l15;
#pragma unroll
            for (int r = 0; r < 4; ++r) {
                const int qg = q0 + wave * 16 + quad * 4 + r;
                const float v = sacc[nt][r] * 0.125f;
                sacc[nt][r] = (jg > qg) ? -1e9f : v;
            }
        }

        // --- online softmax; rows live in 16-lane groups -> 4 shuffle rounds ---
        float rmax[4];
#pragma unroll
        for (int r = 0; r < 4; ++r)
            rmax[r] = fmaxf(fmaxf(sacc[0][r], sacc[1][r]), fmaxf(sacc[2][r], sacc[3][r]));
#pragma unroll
        for (int off = 1; off < 16; off <<= 1)
#pragma unroll
            for (int r = 0; r < 4; ++r)
                rmax[r] = fmaxf(rmax[r], __shfl_xor(rmax[r], off));

        float alpha[4];
#pragma unroll
        for (int r = 0; r < 4; ++r) {
            const float mn = fmaxf(m_r[r], rmax[r]);
            alpha[r] = __expf(m_r[r] - mn);
            m_r[r] = mn;
        }

        float rsum[4] = {0.f, 0.f, 0.f, 0.f};
#pragma unroll
        for (int nt = 0; nt < 4; ++nt)
#pragma unroll
            for (int r = 0; r < 4; ++r) {
                const float p = __expf(sacc[nt][r] - m_r[r]);
                sacc[nt][r] = p;
                rsum[r] += p;
            }
#pragma unroll
        for (int off = 1; off < 16; off <<= 1)
#pragma unroll
            for (int r = 0; r < 4; ++r)
                rsum[r] += __shfl_xor(rsum[r], off);
#pragma unroll
        for (int r = 0; r < 4; ++r)
            l_r[r] = l_r[r] * alpha[r] + rsum[r];

#pragma unroll
        for (int nt = 0; nt < 4; ++nt)
#pragma unroll
            for (int r = 0; r < 4; ++r)
                oacc[nt][r] *= alpha[r];

        // --- P (C-layout) -> LDS -> A-layout. Per-wave strip, no block barrier:
        // within-wave LDS ordering guaranteed after lgkmcnt(0) drain.
#pragma unroll
        for (int nt = 0; nt < 4; ++nt)
#pragma unroll
            for (int r = 0; r < 4; ++r)
                Pb[wave][quad * 4 + r][nt * 16 + l15] = (short)f2bf(sacc[nt][r]);
        __asm__ volatile("s_waitcnt lgkmcnt(0)" ::: "memory");

        // --- O += P @ V ---
        short8 af[2];
        af[0] = *(const short8*)&Pb[wave][l15][quad * 8];
        af[1] = *(const short8*)&Pb[wave][l15][32 + quad * 8];
#pragma unroll
        for (int nt = 0; nt < 4; ++nt) {
            const int dk = nt * 16 + l15;
#pragma unroll
            for (int ks = 0; ks < 2; ++ks) {
                const short8 bv = *(const short8*)&Vts[dk][ks * 32 + quad * 8];
                oacc[nt] = __builtin_amdgcn_mfma_f32_16x16x32_bf16(af[ks], bv, oacc[nt], 0, 0, 0);
            }
        }
        __syncthreads();   // all waves done with Khi/Klo/Vts before restaging
    }

    // --- epilogue: normalize, write concat layout [q][h*64+dk] ---
#pragma unroll
    for (int r = 0; r < 4; ++r) {
        const float inv = 1.0f / l_r[r];
        const int qg = q0 + wave * 16 + quad * 4 + r;
        float* op = Oc + (size_t)qg * DMODEL + h * 64 + l15;
#pragma unroll
        for (int nt = 0; nt < 4; ++nt)
            op[nt * 16] = oacc[nt][r] * inv;
    }
}

extern "C" void kernel_launch(void* const* d_in, const int* in_sizes, int n_in,
                              void* d_out, int out_size, void* d_ws, size_t ws_size,
                              hipStream_t stream)
{
    const float* Q  = (const float*)d_in[0];
    const float* K  = (const float*)d_in[1];
    const float* V  = (const float*)d_in[2];
    const float* WQ = (const float*)d_in[3];
    const float* WK = (const float*)d_in[4];
    const float* WV = (const float*)d_in[5];
    const float* WO = (const float*)d_in[6];

    float* out = (float*)d_out;
    float* ws  = (float*)d_ws;

    const size_t SD = (size_t)S * DMODEL;
    float* Qc = ws;
    float* Kc = ws + SD;
    float* Vc = ws + 2 * SD;
    float* Oc = ws + 3 * SD;

    proj_all<<<dim3(S / 128, DMODEL / 64, 3), 256, 0, stream>>>(
        Q, K, V, WQ, WK, WV, Qc, Kc, Vc);

    attn_mfma<<<dim3((S / 64) * H), 256, 0, stream>>>(Qc, Kc, Vc, Oc);

    out_gemm<<<dim3(S / 128, DMODEL / 64), 256, 0, stream>>>(Oc, WO, out);
}

// Round 3
// 406.066 us; speedup vs baseline: 3.1087x; 1.8333x over previous
//
#include <hip/hip_runtime.h>
#include <hip/hip_bf16.h>

// Problem constants
constexpr int S      = 4096;
constexpr int DMODEL = 1024;
constexpr int H      = 16;
constexpr int DK     = 64;

typedef __attribute__((ext_vector_type(8))) short          short8;
typedef __attribute__((ext_vector_type(4))) short          short4v;
typedef __attribute__((ext_vector_type(4))) float          float4v;
typedef __attribute__((ext_vector_type(4))) unsigned short ushort4v;
typedef __attribute__((ext_vector_type(8))) unsigned short ushort8;

// RNE float -> bf16 (bit pattern), and back
__device__ __forceinline__ unsigned short f2bf(float x) {
    unsigned u = __builtin_bit_cast(unsigned, x);
    u += 0x7FFFu + ((u >> 16) & 1u);
    return (unsigned short)(u >> 16);
}
__device__ __forceinline__ float bf2f(unsigned short h) {
    unsigned u = ((unsigned)h) << 16;
    return __builtin_bit_cast(float, u);
}

// ---------------------------------------------------------------------------
// Prep 1: elementwise split of X inputs.  z=0: Q -> QH/QL, z=1: K -> KH/KL,
// z=2: V -> Vb (plain bf16).  Layout preserved [4096][1024].
// ---------------------------------------------------------------------------
__global__ __launch_bounds__(256) void split_inputs(const float* __restrict__ Q,
                                                    const float* __restrict__ K,
                                                    const float* __restrict__ V,
                                                    unsigned short* __restrict__ QH,
                                                    unsigned short* __restrict__ QL,
                                                    unsigned short* __restrict__ KH,
                                                    unsigned short* __restrict__ KL,
                                                    unsigned short* __restrict__ Vb)
{
    const int z = blockIdx.z;
    const size_t base = ((size_t)blockIdx.x * 256 + threadIdx.x) * 8;
    const float* src = (z == 0) ? Q : (z == 1) ? K : V;
    const float4 a = *(const float4*)(src + base);
    const float4 b = *(const float4*)(src + base + 4);
    const float xs[8] = {a.x, a.y, a.z, a.w, b.x, b.y, b.z, b.w};
    ushort8 hv, lv;
#pragma unroll
    for (int j = 0; j < 8; ++j) {
        const unsigned short h = f2bf(xs[j]);
        hv[j] = h;
        lv[j] = f2bf(xs[j] - bf2f(h));
    }
    if (z == 0)      { *(ushort8*)(QH + base) = hv; *(ushort8*)(QL + base) = lv; }
    else if (z == 1) { *(ushort8*)(KH + base) = hv; *(ushort8*)(KL + base) = lv; }
    else             { *(ushort8*)(Vb + base) = hv; }
}

// ---------------------------------------------------------------------------
// Prep 2: transpose (+ optional split) of weight slabs to [n][k] bf16.
// Slab z: input element (r, c) at in[z*z_mult + r*rstride + c], r in [0,1024),
// c in [0,64).  Output row n = z*64 + c, col k = r:  out[n*1024 + k].
//   WQ/WK/WV headed [h][d][64]: z_mult=65536, rstride=64, z=head
//   WO flat [d][1024]:          z_mult=64,    rstride=1024, z=column-slab
// ---------------------------------------------------------------------------
__global__ __launch_bounds__(256) void transpose_w(const float* __restrict__ in,
                                                   unsigned short* __restrict__ oh,
                                                   unsigned short* __restrict__ ol,
                                                   int z_mult, int rstride)
{
    __shared__ float Ts[64][65];
    const int t  = threadIdx.x;
    const int z  = blockIdx.z;
    const int r0 = blockIdx.x * 64;
    const float* src = in + (size_t)z * z_mult;
#pragma unroll
    for (int i = 0; i < 4; ++i) {
        const int row = (t >> 4) + i * 16;
        const int col = (t & 15) * 4;
        const float4 v = *(const float4*)&src[(size_t)(r0 + row) * rstride + col];
        Ts[row][col + 0] = v.x; Ts[row][col + 1] = v.y;
        Ts[row][col + 2] = v.z; Ts[row][col + 3] = v.w;
    }
    __syncthreads();
#pragma unroll
    for (int i = 0; i < 4; ++i) {
        const int c  = (t >> 4) + i * 16;   // out-row (input col)
        const int rb = (t & 15) * 4;        // out-col base (input row)
        ushort4v hv, lv;
#pragma unroll
        for (int j = 0; j < 4; ++j) {
            const float x = Ts[rb + j][c];
            const unsigned short h = f2bf(x);
            hv[j] = h;
            lv[j] = f2bf(x - bf2f(h));
        }
        const size_t o = (size_t)(z * 64 + c) * 1024 + r0 + rb;
        *(ushort4v*)&oh[o] = hv;
        if (ol) *(ushort4v*)&ol[o] = lv;
    }
}

// ---------------------------------------------------------------------------
// bf16 MFMA GEMM core: C[m][n] (fp32, stride 1024) = A @ B
//   A (hi/lo) : [4096][1024] bf16, [m][k] row-major
//   B (hi/lo) : [1024][1024] bf16, [n][k] (pre-transposed)
// Tile 128x128, BK=32, 256 threads = 4 waves, each wave 64x64 (4x4 MFMA tiles).
// SPLIT: C += Ah*Bh + Ah*Bl + Al*Bh  (near-fp32; drops lo*lo ~2^-16 rel).
// smem: SPLIT ? 32 KB : 16 KB (caller provides).
// ---------------------------------------------------------------------------
template <bool SPLIT>
__device__ __forceinline__ void gemm_core(unsigned short* __restrict__ sm,
                                          const unsigned short* __restrict__ Ah,
                                          const unsigned short* __restrict__ Al,
                                          const unsigned short* __restrict__ Bh,
                                          const unsigned short* __restrict__ Bl,
                                          float* __restrict__ C,
                                          int m0, int n0)
{
    unsigned short* AsH = sm;            // [128][32]
    unsigned short* BsH = sm + 4096;
    unsigned short* AsL = sm + 8192;     // used only if SPLIT
    unsigned short* BsL = sm + 12288;

    const int t    = threadIdx.x;
    const int wave = t >> 6;
    const int lane = t & 63;
    const int quad = lane >> 4;
    const int l15  = lane & 15;
    const int wm   = (wave & 1) * 64;
    const int wn   = (wave >> 1) * 64;

    float4v acc[4][4];
#pragma unroll
    for (int mi = 0; mi < 4; ++mi)
#pragma unroll
        for (int ni = 0; ni < 4; ++ni)
#pragma unroll
            for (int r = 0; r < 4; ++r) acc[mi][ni][r] = 0.f;

    for (int k0 = 0; k0 < 1024; k0 += 32) {
        __syncthreads();   // previous iteration's LDS reads complete
#pragma unroll
        for (int i = 0; i < 2; ++i) {
            const int c   = t + 256 * i;
            const int row = c >> 2;
            const int kc  = (c & 3) * 8;
            *(ushort8*)&AsH[row * 32 + kc] =
                *(const ushort8*)&Ah[(size_t)(m0 + row) * 1024 + k0 + kc];
            *(ushort8*)&BsH[row * 32 + kc] =
                *(const ushort8*)&Bh[(size_t)(n0 + row) * 1024 + k0 + kc];
            if (SPLIT) {
                *(ushort8*)&AsL[row * 32 + kc] =
                    *(const ushort8*)&Al[(size_t)(m0 + row) * 1024 + k0 + kc];
                *(ushort8*)&BsL[row * 32 + kc] =
                    *(const ushort8*)&Bl[(size_t)(n0 + row) * 1024 + k0 + kc];
            }
        }
        __syncthreads();

        short8 afh[4], bfh[4], afl[4], bfl[4];
#pragma unroll
        for (int mi = 0; mi < 4; ++mi)
            afh[mi] = *(const short8*)&AsH[(wm + mi * 16 + l15) * 32 + quad * 8];
#pragma unroll
        for (int ni = 0; ni < 4; ++ni)
            bfh[ni] = *(const short8*)&BsH[(wn + ni * 16 + l15) * 32 + quad * 8];
        if (SPLIT) {
#pragma unroll
            for (int mi = 0; mi < 4; ++mi)
                afl[mi] = *(const short8*)&AsL[(wm + mi * 16 + l15) * 32 + quad * 8];
#pragma unroll
            for (int ni = 0; ni < 4; ++ni)
                bfl[ni] = *(const short8*)&BsL[(wn + ni * 16 + l15) * 32 + quad * 8];
        }

#pragma unroll
        for (int mi = 0; mi < 4; ++mi)
#pragma unroll
            for (int ni = 0; ni < 4; ++ni) {
                acc[mi][ni] = __builtin_amdgcn_mfma_f32_16x16x32_bf16(
                    afh[mi], bfh[ni], acc[mi][ni], 0, 0, 0);
                if (SPLIT) {
                    acc[mi][ni] = __builtin_amdgcn_mfma_f32_16x16x32_bf16(
                        afh[mi], bfl[ni], acc[mi][ni], 0, 0, 0);
                    acc[mi][ni] = __builtin_amdgcn_mfma_f32_16x16x32_bf16(
                        afl[mi], bfh[ni], acc[mi][ni], 0, 0, 0);
                }
            }
    }

#pragma unroll
    for (int mi = 0; mi < 4; ++mi)
#pragma unroll
        for (int r = 0; r < 4; ++r) {
            const int m = m0 + wm + mi * 16 + quad * 4 + r;
            float* cp = C + (size_t)m * 1024 + n0 + wn + l15;
#pragma unroll
            for (int ni = 0; ni < 4; ++ni) cp[ni * 16] = acc[mi][ni][r];
        }
}

// Fused projections: z=0 Q(split), z=1 K(split), z=2 V(plain)
__global__ __launch_bounds__(256) void proj_mfma(
    const unsigned short* __restrict__ XqH, const unsigned short* __restrict__ XqL,
    const unsigned short* __restrict__ XkH, const unsigned short* __restrict__ XkL,
    const unsigned short* __restrict__ Xv,
    const unsigned short* __restrict__ WqtH, const unsigned short* __restrict__ WqtL,
    const unsigned short* __restrict__ WktH, const unsigned short* __restrict__ WktL,
    const unsigned short* __restrict__ Wvt,
    float* __restrict__ Qc, float* __restrict__ Kc, float* __restrict__ Vc)
{
    __shared__ __align__(16) unsigned short smem[4 * 4096];
    const int m0 = blockIdx.x * 128, n0 = blockIdx.y * 128;
    if (blockIdx.z == 0)
        gemm_core<true>(smem, XqH, XqL, WqtH, WqtL, Qc, m0, n0);
    else if (blockIdx.z == 1)
        gemm_core<true>(smem, XkH, XkL, WktH, WktL, Kc, m0, n0);
    else
        gemm_core<false>(smem, Xv, nullptr, Wvt, nullptr, Vc, m0, n0);
}

__global__ __launch_bounds__(256) void out_gemm_mfma(
    const unsigned short* __restrict__ Ocb,
    const unsigned short* __restrict__ WOt,
    float* __restrict__ out)
{
    __shared__ __align__(16) unsigned short smem[2 * 4096];
    gemm_core<false>(smem, Ocb, nullptr, WOt, nullptr, out,
                     blockIdx.x * 128, blockIdx.y * 128);
}

// ---------------------------------------------------------------------------
// MFMA flash attention (validated round 2).  One block = (head, 64-row Q tile).
// Score path split-bf16; PV plain bf16.  Epilogue now writes bf16 Ocb.
// ---------------------------------------------------------------------------
__global__ __launch_bounds__(256) void attn_mfma(const float* __restrict__ Qc,
                                                 const float* __restrict__ Kc,
                                                 const float* __restrict__ Vc,
                                                 unsigned short* __restrict__ Ocb)
{
    __shared__ __align__(16) short Khi[64][72];
    __shared__ __align__(16) short Klo[64][72];
    __shared__ __align__(16) short Vts[64][72];
    __shared__ __align__(16) short Pb[4][16][72];

    const int bid = blockIdx.x;
    const int h   = bid & 15;
    const int qt  = 63 - (bid >> 4);
    const int q0  = qt * 64;

    const int t    = threadIdx.x;
    const int wave = t >> 6;
    const int lane = t & 63;
    const int quad = lane >> 4;
    const int l15  = lane & 15;

    short8 qhi[2], qlo[2];
    {
        const int qrow = q0 + wave * 16 + l15;
        const float* qp = Qc + (size_t)qrow * DMODEL + h * 64 + quad * 8;
#pragma unroll
        for (int ks = 0; ks < 2; ++ks) {
            float4 a = *(const float4*)(qp + ks * 32);
            float4 b = *(const float4*)(qp + ks * 32 + 4);
            const float xs[8] = {a.x, a.y, a.z, a.w, b.x, b.y, b.z, b.w};
#pragma unroll
            for (int j = 0; j < 8; ++j) {
                const unsigned short hi = f2bf(xs[j]);
                const unsigned short lo = f2bf(xs[j] - bf2f(hi));
                qhi[ks][j] = (short)hi;
                qlo[ks][j] = (short)lo;
            }
        }
    }

    float m_r[4] = {-1e30f, -1e30f, -1e30f, -1e30f};
    float l_r[4] = {0.f, 0.f, 0.f, 0.f};
    float4v oacc[4];
#pragma unroll
    for (int nt = 0; nt < 4; ++nt)
#pragma unroll
        for (int r = 0; r < 4; ++r) oacc[nt][r] = 0.f;

    const int sr  = t >> 2;
    const int sc0 = (t & 3) * 16;

    for (int jt = 0; jt <= qt; ++jt) {
        const int j0 = jt * 64;
        const float* kp = Kc + (size_t)(j0 + sr) * DMODEL + h * 64 + sc0;
        const float* vp = Vc + (size_t)(j0 + sr) * DMODEL + h * 64 + sc0;
#pragma unroll
        for (int ch = 0; ch < 4; ++ch) {
            const float4 f = *(const float4*)(kp + ch * 4);
            const float xs[4] = {f.x, f.y, f.z, f.w};
            short4v hv, lv;
#pragma unroll
            for (int j = 0; j < 4; ++j) {
                const unsigned short hi = f2bf(xs[j]);
                const unsigned short lo = f2bf(xs[j] - bf2f(hi));
                hv[j] = (short)hi;
                lv[j] = (short)lo;
            }
            *(short4v*)&Khi[sr][sc0 + ch * 4] = hv;
            *(short4v*)&Klo[sr][sc0 + ch * 4] = lv;
            const float4 g = *(const float4*)(vp + ch * 4);
            Vts[sc0 + ch * 4 + 0][sr] = (short)f2bf(g.x);
            Vts[sc0 + ch * 4 + 1][sr] = (short)f2bf(g.y);
            Vts[sc0 + ch * 4 + 2][sr] = (short)f2bf(g.z);
            Vts[sc0 + ch * 4 + 3][sr] = (short)f2bf(g.w);
        }
        __syncthreads();

        float4v sacc[4];
#pragma unroll
        for (int nt = 0; nt < 4; ++nt)
#pragma unroll
            for (int r = 0; r < 4; ++r) sacc[nt][r] = 0.f;
#pragma unroll
        for (int nt = 0; nt < 4; ++nt) {
            const int key = nt * 16 + l15;
#pragma unroll
            for (int ks = 0; ks < 2; ++ks) {
                const short8 bh = *(const short8*)&Khi[key][ks * 32 + quad * 8];
                const short8 bl = *(const short8*)&Klo[key][ks * 32 + quad * 8];
                sacc[nt] = __builtin_amdgcn_mfma_f32_16x16x32_bf16(qhi[ks], bh, sacc[nt], 0, 0, 0);
                sacc[nt] = __builtin_amdgcn_mfma_f32_16x16x32_bf16(qhi[ks], bl, sacc[nt], 0, 0, 0);
                sacc[nt] = __builtin_amdgcn_mfma_f32_16x16x32_bf16(qlo[ks], bh, sacc[nt], 0, 0, 0);
            }
        }

#pragma unroll
        for (int nt = 0; nt < 4; ++nt) {
            const int jg = j0 + nt * 16 + l15;
#pragma unroll
            for (int r = 0; r < 4; ++r) {
                const int qg = q0 + wave * 16 + quad * 4 + r;
                const float v = sacc[nt][r] * 0.125f;
                sacc[nt][r] = (jg > qg) ? -1e9f : v;
            }
        }

        float rmax[4];
#pragma unroll
        for (int r = 0; r < 4; ++r)
            rmax[r] = fmaxf(fmaxf(sacc[0][r], sacc[1][r]), fmaxf(sacc[2][r], sacc[3][r]));
#pragma unroll
        for (int off = 1; off < 16; off <<= 1)
#pragma unroll
            for (int r = 0; r < 4; ++r)
                rmax[r] = fmaxf(rmax[r], __shfl_xor(rmax[r], off));

        float alpha[4];
#pragma unroll
        for (int r = 0; r < 4; ++r) {
            const float mn = fmaxf(m_r[r], rmax[r]);
            alpha[r] = __expf(m_r[r] - mn);
            m_r[r] = mn;
        }

        float rsum[4] = {0.f, 0.f, 0.f, 0.f};
#pragma unroll
        for (int nt = 0; nt < 4; ++nt)
#pragma unroll
            for (int r = 0; r < 4; ++r) {
                const float p = __expf(sacc[nt][r] - m_r[r]);
                sacc[nt][r] = p;
                rsum[r] += p;
            }
#pragma unroll
        for (int off = 1; off < 16; off <<= 1)
#pragma unroll
            for (int r = 0; r < 4; ++r)
                rsum[r] += __shfl_xor(rsum[r], off);
#pragma unroll
        for (int r = 0; r < 4; ++r)
            l_r[r] = l_r[r] * alpha[r] + rsum[r];

#pragma unroll
        for (int nt = 0; nt < 4; ++nt)
#pragma unroll
            for (int r = 0; r < 4; ++r)
                oacc[nt][r] *= alpha[r];

#pragma unroll
        for (int nt = 0; nt < 4; ++nt)
#pragma unroll
            for (int r = 0; r < 4; ++r)
                Pb[wave][quad * 4 + r][nt * 16 + l15] = (short)f2bf(sacc[nt][r]);
        __asm__ volatile("s_waitcnt lgkmcnt(0)" ::: "memory");

        short8 af[2];
        af[0] = *(const short8*)&Pb[wave][l15][quad * 8];
        af[1] = *(const short8*)&Pb[wave][l15][32 + quad * 8];
#pragma unroll
        for (int nt = 0; nt < 4; ++nt) {
            const int dk = nt * 16 + l15;
#pragma unroll
            for (int ks = 0; ks < 2; ++ks) {
                const short8 bv = *(const short8*)&Vts[dk][ks * 32 + quad * 8];
                oacc[nt] = __builtin_amdgcn_mfma_f32_16x16x32_bf16(af[ks], bv, oacc[nt], 0, 0, 0);
            }
        }
        __syncthreads();
    }

#pragma unroll
    for (int r = 0; r < 4; ++r) {
        const float inv = 1.0f / l_r[r];
        const int qg = q0 + wave * 16 + quad * 4 + r;
        unsigned short* op = Ocb + (size_t)qg * DMODEL + h * 64 + l15;
#pragma unroll
        for (int nt = 0; nt < 4; ++nt)
            op[nt * 16] = f2bf(oacc[nt][r] * inv);
    }
}

extern "C" void kernel_launch(void* const* d_in, const int* in_sizes, int n_in,
                              void* d_out, int out_size, void* d_ws, size_t ws_size,
                              hipStream_t stream)
{
    const float* Q  = (const float*)d_in[0];
    const float* K  = (const float*)d_in[1];
    const float* V  = (const float*)d_in[2];
    const float* WQ = (const float*)d_in[3];
    const float* WK = (const float*)d_in[4];
    const float* WV = (const float*)d_in[5];
    const float* WO = (const float*)d_in[6];

    float* out = (float*)d_out;

    // Workspace carve-up (total 108 MB)
    const size_t SD4 = (size_t)S * DMODEL * 4;   // fp32 S x D      (16 MB)
    const size_t SD2 = (size_t)S * DMODEL * 2;   // bf16 S x D      ( 8 MB)
    const size_t W2  = (size_t)DMODEL * DMODEL * 2;  // bf16 D x D  ( 2 MB)
    char* p = (char*)d_ws;
    auto take = [&](size_t b) { char* r = p; p += b; return r; };

    float* Qc = (float*)take(SD4);
    float* Kc = (float*)take(SD4);
    float* Vc = (float*)take(SD4);
    unsigned short* XqH = (unsigned short*)take(SD2);
    unsigned short* XqL = (unsigned short*)take(SD2);
    unsigned short* XkH = (unsigned short*)take(SD2);
    unsigned short* XkL = (unsigned short*)take(SD2);
    unsigned short* Xv  = (unsigned short*)take(SD2);
    unsigned short* WqtH = (unsigned short*)take(W2);
    unsigned short* WqtL = (unsigned short*)take(W2);
    unsigned short* WktH = (unsigned short*)take(W2);
    unsigned short* WktL = (unsigned short*)take(W2);
    unsigned short* Wvt  = (unsigned short*)take(W2);
    unsigned short* WOt  = (unsigned short*)take(W2);
    unsigned short* Ocb  = (unsigned short*)take(SD2);

    // 1) input splits (Q,K hi/lo; V bf16)
    split_inputs<<<dim3(2048, 1, 3), 256, 0, stream>>>(Q, K, V,
                                                       XqH, XqL, XkH, XkL, Xv);
    // 2) weight transposes to [n][k] bf16 (Q,K split; V,O plain)
    transpose_w<<<dim3(16, 1, 16), 256, 0, stream>>>(WQ, WqtH, WqtL, 65536, 64);
    transpose_w<<<dim3(16, 1, 16), 256, 0, stream>>>(WK, WktH, WktL, 65536, 64);
    transpose_w<<<dim3(16, 1, 16), 256, 0, stream>>>(WV, Wvt, nullptr, 65536, 64);
    transpose_w<<<dim3(16, 1, 16), 256, 0, stream>>>(WO, WOt, nullptr, 64, 1024);
    // 3) projections (MFMA; Q,K split-bf16, V plain) -> fp32 concat layouts
    proj_mfma<<<dim3(S / 128, DMODEL / 128, 3), 256, 0, stream>>>(
        XqH, XqL, XkH, XkL, Xv, WqtH, WqtL, WktH, WktL, Wvt, Qc, Kc, Vc);
    // 4) causal flash attention (MFMA) -> bf16 Ocb
    attn_mfma<<<dim3((S / 64) * H), 256, 0, stream>>>(Qc, Kc, Vc, Ocb);
    // 5) output projection (plain bf16 MFMA)
    out_gemm_mfma<<<dim3(S / 128, DMODEL / 128), 256, 0, stream>>>(Ocb, WOt, out);
}